// Round 1
// baseline (312.476 us; speedup 1.0000x reference)
//
#include <hip/hip_runtime.h>

// ROIAlign3d for x=[2,256,16,64,64] f32, rois=[64,5] -> out=[64,256,16,7,7] f32.
// One thread per output element. Per-block LDS table of sample offsets/weights
// (depends only on (r, ph, pw); 784 blocks per roi, block never crosses roi).

#define NBINS 49   // 7*7
#define NSAMP 4    // 2x2 sample grid per bin

__global__ __launch_bounds__(256) void roialign3d_kernel(
    const float* __restrict__ x, const float* __restrict__ rois,
    float* __restrict__ out)
{
    constexpr int C = 256, T = 16, H = 64, W = 64;
    constexpr float SCALE = 0.0625f;

    const int r = blockIdx.x / 784;   // uniform per block

    __shared__ int4   s_off[NSAMP * NBINS];  // 4 corner offsets per (s, bin)
    __shared__ float4 s_w[NSAMP * NBINS];    // 4 corner weights (mask * 0.25 folded)

    // ---- build sample table (cheap, redundant per block, ~196 entries) ----
    const float r1 = rois[r * 5 + 1], r2 = rois[r * 5 + 2];
    const float r3 = rois[r * 5 + 3], r4 = rois[r * 5 + 4];
    const int   bidx = (int)rois[r * 5 + 0];

    const float sw_ = r1 * SCALE, sh_ = r2 * SCALE;
    const float ew_ = r3 * SCALE, eh_ = r4 * SCALE;
    const float roi_w = fmaxf(ew_ - sw_, 1.0f);
    const float roi_h = fmaxf(eh_ - sh_, 1.0f);
    const float bin_w = roi_w * (1.0f / 7.0f);
    const float bin_h = roi_h * (1.0f / 7.0f);

    for (int i = threadIdx.x; i < NSAMP * NBINS; i += 256) {
        const int s  = i / NBINS;       // 0..3 = gy*2+gx
        const int pp = i - s * NBINS;   // 0..48
        const int ph = pp / 7, pw = pp - ph * 7;
        const int gy = s >> 1, gx = s & 1;
        const float gyf = ((float)gy + 0.5f) * 0.5f;
        const float gxf = ((float)gx + 0.5f) * 0.5f;

        const float ys = sh_ + ((float)ph + gyf) * bin_h;
        const float xs = sw_ + ((float)pw + gxf) * bin_w;

        const bool vy = (ys >= -1.0f) && (ys <= (float)H);
        const bool vx = (xs >= -1.0f) && (xs <= (float)W);

        const float yc = fminf(fmaxf(ys, 0.0f), (float)(H - 1));
        const int   y0 = (int)floorf(yc);
        const int   y1 = min(y0 + 1, H - 1);
        const float ly = yc - (float)y0, hy = 1.0f - ly;

        const float xc = fminf(fmaxf(xs, 0.0f), (float)(W - 1));
        const int   x0 = (int)floorf(xc);
        const int   x1 = min(x0 + 1, W - 1);
        const float lx = xc - (float)x0, hx = 1.0f - lx;

        const float m = (vy && vx) ? 0.25f : 0.0f;

        s_off[i] = make_int4(y0 * W + x0, y0 * W + x1, y1 * W + x0, y1 * W + x1);
        s_w[i]   = make_float4(hy * hx * m, hy * lx * m, ly * hx * m, ly * lx * m);
    }
    __syncthreads();

    // ---- one output element per thread, fully coalesced store ----
    const int o  = blockIdx.x * 256 + threadIdx.x;      // < 12,845,056
    const int pp = o % 49;
    const int q  = o / 49;          // = (r*C + c)*T + t
    const int t  = q & (T - 1);
    const int ct = q >> 4;          // = r*C + c
    const int c  = ct & (C - 1);

    const float* __restrict__ plane =
        x + ((size_t)(((bidx * C + c) * T) + t) << 12);   // * H*W(=4096)

    float acc = 0.0f;
#pragma unroll
    for (int s = 0; s < NSAMP; s++) {
        const int4   off = s_off[s * NBINS + pp];
        const float4 w   = s_w[s * NBINS + pp];
        acc += w.x * plane[off.x] + w.y * plane[off.y] +
               w.z * plane[off.z] + w.w * plane[off.w];
    }
    out[o] = acc;
}

extern "C" void kernel_launch(void* const* d_in, const int* in_sizes, int n_in,
                              void* d_out, int out_size, void* d_ws, size_t ws_size,
                              hipStream_t stream) {
    const float* x    = (const float*)d_in[0];   // 2*256*16*64*64
    const float* rois = (const float*)d_in[1];   // 64*5
    float* out = (float*)d_out;                  // 64*256*16*7*7 = 12,845,056

    // 12,845,056 / 256 = 50,176 blocks; 784 blocks per roi (exact)
    roialign3d_kernel<<<dim3(50176), dim3(256), 0, stream>>>(x, rois, out);
}

// Round 2
// 305.074 us; speedup vs baseline: 1.0243x; 1.0243x over previous
//
#include <hip/hip_runtime.h>

// ROIAlign3d: x=[2,256,16,64,64] f32, rois=[64,5] -> out=[64,256,16,7,7] f32.
// R2 strategy: block = (roi r, channel c, 4 consecutive t-planes).
//  Phase A: build per-roi sample table (196 entries: LDS-relative offsets +
//           clamp/valid-folded weights) and stage the roi's row range
//           (<=17 full 64-float rows per plane) into LDS via coalesced float4.
//  Phase B: 196 threads compute one output each from LDS (8 paired reads),
//           contiguous 196-float store.
// This removes the 16 scattered global gathers/thread (TA-transaction bound
// at ~170us) in favor of coalesced staging + LDS reads.

#define NBINS 49
#define NSAMP 4
#define P     4          // t-planes per block
#define MAXR  18         // max rows in roi box (spread <= 6.5*16/7 + 2)
#define RSTR  68         // LDS row stride (floats): 64 cols + pad, mult of 4
#define PLANE (MAXR * RSTR)

__global__ __launch_bounds__(256) void roialign3d_kernel(
    const float* __restrict__ x, const float* __restrict__ rois,
    float* __restrict__ out)
{
    constexpr int C = 256, T = 16, H = 64, W = 64;
    constexpr float SCALE = 0.0625f;

    __shared__ float s_box[P * PLANE];          // 4*18*68*4 = 19584 B
    __shared__ int2   s_off[NSAMP * NBINS];     // (offA, offB) row-pair bases
    __shared__ float4 s_wt[NSAMP * NBINS];      // folded weights

    const int b  = blockIdx.x;
    const int t0 = (b & 3) * P;
    const int c  = (b >> 2) & 255;
    const int r  = b >> 10;
    const int tid = threadIdx.x;

    // ---- uniform roi params ----
    const float r1 = rois[r * 5 + 1], r2 = rois[r * 5 + 2];
    const float r3 = rois[r * 5 + 3], r4 = rois[r * 5 + 4];
    const int   bidx = (int)rois[r * 5 + 0];

    const float sw_ = r1 * SCALE, sh_ = r2 * SCALE;
    const float ew_ = r3 * SCALE, eh_ = r4 * SCALE;
    const float bin_w = fmaxf(ew_ - sw_, 1.0f) * (1.0f / 7.0f);
    const float bin_h = fmaxf(eh_ - sh_, 1.0f) * (1.0f / 7.0f);

    // row range of the sampled box (samples are monotone in y)
    const float ys_first = sh_ + 0.25f * bin_h;
    const float ys_last  = sh_ + 6.75f * bin_h;
    const int y_lo = (int)floorf(fminf(fmaxf(ys_first, 0.0f), (float)(H - 1)));
    const int y_hi = min((int)floorf(fminf(fmaxf(ys_last, 0.0f), (float)(H - 1))) + 1, H - 1);
    const int nr   = y_hi - y_lo + 1;            // <= 17

    // ---- Phase A1: sample table (196 entries) ----
    if (tid < NSAMP * NBINS) {
        const int s  = tid / NBINS;
        const int pp = tid - s * NBINS;
        const int ph = pp / 7, pw = pp - ph * 7;
        const float gyf = ((float)(s >> 1) + 0.5f) * 0.5f;
        const float gxf = ((float)(s & 1) + 0.5f) * 0.5f;

        const float ys = sh_ + ((float)ph + gyf) * bin_h;
        const float xs = sw_ + ((float)pw + gxf) * bin_w;

        const bool vy = (ys >= -1.0f) && (ys <= (float)H);
        const bool vx = (xs >= -1.0f) && (xs <= (float)W);

        const float yc = fminf(fmaxf(ys, 0.0f), (float)(H - 1));
        const int   y0 = (int)floorf(yc);
        const float ly = yc - (float)y0, hy = 1.0f - ly;
        const int   y1 = min(y0 + 1, H - 1);

        const float xc = fminf(fmaxf(xs, 0.0f), (float)(W - 1));
        const int   x0 = (int)floorf(xc);
        const float lx = xc - (float)x0, hx = 1.0f - lx;
        const bool  xpair = (x0 < W - 1);        // x1 == x0+1 ?

        // fold x-clamp: always read cols (x0, x0+1); if clamped, col x0 gets
        // hx+lx and the pad/next col gets 0.
        const float wxh = xpair ? hx : (hx + lx);
        const float wxl = xpair ? lx : 0.0f;
        const float m   = (vy && vx) ? 0.25f : 0.0f;

        s_off[tid] = make_int2((y0 - y_lo) * RSTR + x0,
                               (y1 - y_lo) * RSTR + x0);
        s_wt[tid]  = make_float4(hy * wxh * m, hy * wxl * m,
                                 ly * wxh * m, ly * wxl * m);
    }

    // zero pad col 64 (read with weight 0 when x0 == 63)
    if (tid < P * MAXR) {
        const int p = tid / MAXR, rw = tid - p * MAXR;
        s_box[p * PLANE + rw * RSTR + 64] = 0.0f;
    }

    // ---- Phase A2: stage rows [y_lo, y_hi] of 4 planes, coalesced float4 ----
    {
        const int row  = tid >> 4;            // 0..15
        const int col4 = (tid & 15) << 2;     // 0,4,...,60
        const size_t pbase0 = ((size_t)((bidx * C + c) * T + t0)) << 12;
#pragma unroll
        for (int p = 0; p < P; ++p) {
            const float* __restrict__ plane = x + pbase0 + ((size_t)p << 12);
            for (int rbase = 0; rbase < nr; rbase += 16) {
                const int rr = rbase + row;
                if (rr < nr) {
                    const float4 v = *(const float4*)(plane + (y_lo + rr) * W + col4);
                    *(float4*)&s_box[p * PLANE + rr * RSTR + col4] = v;
                }
            }
        }
    }

    __syncthreads();

    // ---- Phase B: one output per thread (196 active) ----
    if (tid < P * NBINS) {
        const int p  = tid / NBINS;
        const int pp = tid - p * NBINS;
        const float* __restrict__ bx = &s_box[p * PLANE];

        float acc = 0.0f;
#pragma unroll
        for (int s = 0; s < NSAMP; ++s) {
            const int2   o = s_off[s * NBINS + pp];
            const float4 w = s_wt[s * NBINS + pp];
            const float v00 = bx[o.x], v01 = bx[o.x + 1];
            const float v10 = bx[o.y], v11 = bx[o.y + 1];
            acc += w.x * v00 + w.y * v01 + w.z * v10 + w.w * v11;
        }
        // outputs for this block are contiguous: ((r*C+c)*T+t0)*49 + tid
        out[((size_t)((r * C + c) * T + t0)) * NBINS + tid] = acc;
    }
}

extern "C" void kernel_launch(void* const* d_in, const int* in_sizes, int n_in,
                              void* d_out, int out_size, void* d_ws, size_t ws_size,
                              hipStream_t stream) {
    const float* x    = (const float*)d_in[0];
    const float* rois = (const float*)d_in[1];
    float* out = (float*)d_out;

    // 64 rois * 256 channels * 4 t-groups = 65536 blocks
    roialign3d_kernel<<<dim3(65536), dim3(256), 0, stream>>>(x, rois, out);
}

// Round 3
// 253.410 us; speedup vs baseline: 1.2331x; 1.2039x over previous
//
#include <hip/hip_runtime.h>

// ROIAlign3d: x=[2,256,16,64,64] f32, rois=[64,5] -> out=[64,256,16,7,7] f32.
// R3: block = (roi, channel), all 16 t-planes. Stage only the float4-aligned
// roi box (fixed 17 rows x 20 floats) per plane into LDS; sample table (196
// entries, LDS-relative offsets + clamp/valid-folded weights) built once per
// block. Phase B: 784 outputs per block from LDS, contiguous store.

#define NBINS 49
#define NSAMP 4
#define P     16            // t-planes per block (all of T)
#define MAXR  17            // max rows in sample box (6.5*16/7 + 2 < 17)
#define BW    20            // box width in floats (16-wide box + align slack)
#define PSTR  (MAXR * BW)   // 340 floats per plane box
#define NSTAGE (P * MAXR * 5)  // 1360 float4 slots

__global__ __launch_bounds__(256) void roialign3d_kernel(
    const float* __restrict__ x, const float* __restrict__ rois,
    float* __restrict__ out)
{
    constexpr int C = 256, T = 16, H = 64, W = 64;
    constexpr float SCALE = 0.0625f;
    constexpr int TOT = 2 * C * T * H * W;   // 33,554,432 elements

    __shared__ float  s_box[P * PSTR];       // 21,760 B
    __shared__ int2   s_off[NSAMP * NBINS];  //  1,568 B
    __shared__ float4 s_wt[NSAMP * NBINS];   //  3,136 B

    const int b   = blockIdx.x;
    const int c   = b & 255;
    const int r   = b >> 8;
    const int tid = threadIdx.x;

    // ---- uniform roi params ----
    const float r1 = rois[r * 5 + 1], r2 = rois[r * 5 + 2];
    const float r3 = rois[r * 5 + 3], r4 = rois[r * 5 + 4];
    const int   bidx = (int)rois[r * 5 + 0];

    const float sw_ = r1 * SCALE, sh_ = r2 * SCALE;
    const float ew_ = r3 * SCALE, eh_ = r4 * SCALE;
    const float bin_w = fmaxf(ew_ - sw_, 1.0f) * (1.0f / 7.0f);
    const float bin_h = fmaxf(eh_ - sh_, 1.0f) * (1.0f / 7.0f);

    // box origin (samples are monotone in y/x; first sample at +0.25*bin)
    const float ys_f = sh_ + 0.25f * bin_h;
    const float xs_f = sw_ + 0.25f * bin_w;
    const int y_lo  = (int)floorf(fminf(fmaxf(ys_f, 0.0f), (float)(H - 1)));
    const int x_lo  = (int)floorf(fminf(fmaxf(xs_f, 0.0f), (float)(W - 1)));
    const int x4_lo = x_lo & ~3;

    // ---- sample table: 196 entries (threads 196..255 fall through to stage) --
    if (tid < NSAMP * NBINS) {
        const int s  = tid / NBINS;
        const int pp = tid - s * NBINS;
        const int ph = pp / 7, pw = pp - ph * 7;
        const float gyf = ((float)(s >> 1) + 0.5f) * 0.5f;
        const float gxf = ((float)(s & 1) + 0.5f) * 0.5f;

        const float ys = sh_ + ((float)ph + gyf) * bin_h;
        const float xs = sw_ + ((float)pw + gxf) * bin_w;

        const bool vy = (ys >= -1.0f) && (ys <= (float)H);
        const bool vx = (xs >= -1.0f) && (xs <= (float)W);

        const float yc = fminf(fmaxf(ys, 0.0f), (float)(H - 1));
        const int   y0 = (int)floorf(yc);
        const float ly = yc - (float)y0, hy = 1.0f - ly;
        const int   y1 = min(y0 + 1, H - 1);

        const float xc = fminf(fmaxf(xs, 0.0f), (float)(W - 1));
        const int   x0 = (int)floorf(xc);
        const float lx = xc - (float)x0, hx = 1.0f - lx;
        const bool  xpair = (x0 < W - 1);

        const float wxh = xpair ? hx : (hx + lx);   // fold x-clamp into col x0
        const float wxl = xpair ? lx : 0.0f;
        const float m   = (vy && vx) ? 0.25f : 0.0f;

        const int relc = x0 - x4_lo;                // 0..18
        s_off[tid] = make_int2((y0 - y_lo) * BW + relc,
                               (y1 - y_lo) * BW + relc);
        s_wt[tid]  = make_float4(hy * wxh * m, hy * wxl * m,
                                 ly * wxh * m, ly * wxl * m);
    }

    // ---- stage box for 16 planes: fixed 17 rows x 5 float4, coalesced ----
    {
        const int pbase = ((bidx * C + c) * T) << 12;  // element idx of (c, t=0)
        for (int i = tid; i < NSTAGE; i += 256) {       // 6 iters, last partial
            const int p   = i / 85;                     // const-divisor magic
            const int rem = i - p * 85;
            const int row = rem / 5;
            const int col = rem - row * 5;
            const int rowc = min(y_lo + row, H - 1);    // pad rows clamp (never read)
            int sidx = pbase + (p << 12) + (rowc << 6) + x4_lo + (col << 2);
            sidx = min(sidx, TOT - 4);                  // array-end guard for pad cols
            const float4 v = *(const float4*)(x + sidx);
            *(float4*)&s_box[p * PSTR + row * BW + (col << 2)] = v;
        }
    }
    __syncthreads();

    // ---- Phase B: 784 outputs (3 full rounds + 16 tail), contiguous store ----
    const size_t obase = (size_t)b * (T * NBINS);
#pragma unroll
    for (int j = 0; j < 3; ++j) {
        const int oidx = j * 256 + tid;
        const int p  = oidx / 49;
        const int pp = oidx - p * 49;
        const float* __restrict__ bx = &s_box[p * PSTR];
        float acc = 0.0f;
#pragma unroll
        for (int s = 0; s < NSAMP; ++s) {
            const int2   o = s_off[s * NBINS + pp];
            const float4 w = s_wt[s * NBINS + pp];
            acc += w.x * bx[o.x] + w.y * bx[o.x + 1] +
                   w.z * bx[o.y] + w.w * bx[o.y + 1];
        }
        out[obase + oidx] = acc;
    }
    if (tid < 16) {
        const int oidx = 768 + tid;
        const int p  = oidx / 49;
        const int pp = oidx - p * 49;
        const float* __restrict__ bx = &s_box[p * PSTR];
        float acc = 0.0f;
#pragma unroll
        for (int s = 0; s < NSAMP; ++s) {
            const int2   o = s_off[s * NBINS + pp];
            const float4 w = s_wt[s * NBINS + pp];
            acc += w.x * bx[o.x] + w.y * bx[o.x + 1] +
                   w.z * bx[o.y] + w.w * bx[o.y + 1];
        }
        out[obase + oidx] = acc;
    }
}

extern "C" void kernel_launch(void* const* d_in, const int* in_sizes, int n_in,
                              void* d_out, int out_size, void* d_ws, size_t ws_size,
                              hipStream_t stream) {
    const float* x    = (const float*)d_in[0];
    const float* rois = (const float*)d_in[1];
    float* out = (float*)d_out;

    // 64 rois * 256 channels = 16384 blocks; each does all 16 t-planes
    roialign3d_kernel<<<dim3(16384), dim3(256), 0, stream>>>(x, rois, out);
}